// Round 11
// baseline (1130.049 us; speedup 1.0000x reference)
//
#include <hip/hip_runtime.h>

// ---------------------------------------------------------------------------
// GCN forward. Weights fp32->bf16 MFMA, activations: gather buffers in FP8
// (e4m3, HW cvt), GEMM inputs/pool in bf16, accumulation fp32.
// CSR: bucketed radix (dst>>9, 512 nodes/bucket), contiguous per-node lists.
// Aggregate inner loop: R4-proven sub-wave gather, uint2 (8B) fp8 rows.
// R11: epilogue fusion — agg128g fuses gemm2 (LDS h1 tile + proven 32x32x16
// MFMA, h1b eliminated); agg64p fuses pool+count (LDS run-reduce + atomics,
// h2b eliminated). fusedB = csr_build || gemm1. 6 dispatches total.
// ---------------------------------------------------------------------------

typedef __attribute__((ext_vector_type(8))) short bfrag;     // 8 bf16 = 4 VGPR
typedef __attribute__((ext_vector_type(16))) float f32x16;   // MFMA C/D
typedef __attribute__((ext_vector_type(2))) float floatx2;

__device__ __forceinline__ unsigned short f2bf(float f) {
    unsigned int u = __builtin_bit_cast(unsigned int, f);
    u = (u + 0x7FFFu + ((u >> 16) & 1u)) >> 16;
    return (unsigned short)u;
}
__device__ __forceinline__ float bf2f(unsigned int lo16) {
    unsigned int v = lo16 << 16;
    return __builtin_bit_cast(float, v);
}
__device__ __forceinline__ unsigned char f2fp8(float f) {
    return (unsigned char)(__builtin_amdgcn_cvt_pk_fp8_f32(f, f, 0, false) & 0xFF);
}
// 8 fp8 (uint2) -> fp32, acc += f * c   (HW packed converts, 2 vals/op)
__device__ __forceinline__ void macc8f8(float* acc, const uint2& v, float c) {
    floatx2 f0 = __builtin_amdgcn_cvt_pk_f32_fp8((int)v.x, false);
    floatx2 f1 = __builtin_amdgcn_cvt_pk_f32_fp8((int)v.x, true);
    floatx2 f2 = __builtin_amdgcn_cvt_pk_f32_fp8((int)v.y, false);
    floatx2 f3 = __builtin_amdgcn_cvt_pk_f32_fp8((int)v.y, true);
    acc[0] += f0.x * c; acc[1] += f0.y * c;
    acc[2] += f1.x * c; acc[3] += f1.y * c;
    acc[4] += f2.x * c; acc[5] += f2.y * c;
    acc[6] += f3.x * c; acc[7] += f3.y * c;
}

// --- proven R4 gather body: fills acc[8] (self term + edges + butterfly) ---
template <int NC>
__device__ __forceinline__ void gather_node(const uint2* __restrict__ h8,
                                            const float* __restrict__ dis,
                                            const int* __restrict__ rowstart,
                                            const int* __restrict__ csr_src,
                                            int n, int lane, float d, float* acc) {
    constexpr int LPR = NC / 8;   // lanes per row (8B = 8 fp8 each)
    constexpr int RPS = 64 / LPR; // rows (edges) per step
    int sub = lane / LPR;
    int fid = lane % LPR;
#pragma unroll
    for (int i = 0; i < 8; ++i) acc[i] = 0.f;
    if (sub == 0) {
        uint2 hv = h8[(size_t)n * LPR + fid];
        macc8f8(acc, hv, d);
    }
    int beg = rowstart[n], end = rowstart[n + 1];
    for (int e0 = beg; e0 < end; e0 += 64) {
        int idx = e0 + lane;
        int sv = 0;
        float dv = 0.f;
        if (idx < end) {
            sv = __builtin_nontemporal_load(&csr_src[idx]);
            dv = dis[sv];
        }
        int cnt = min(64, end - e0);
        int j = 0;
        for (; j + 4 * RPS <= cnt; j += 4 * RPS) {
            int ja = j + sub, jb = j + RPS + sub, jc2 = j + 2 * RPS + sub,
                jd = j + 3 * RPS + sub;
            int sa = __shfl(sv, ja); float ca = __shfl(dv, ja);
            int sb = __shfl(sv, jb); float cb = __shfl(dv, jb);
            int sc = __shfl(sv, jc2); float cc = __shfl(dv, jc2);
            int sd = __shfl(sv, jd); float cd = __shfl(dv, jd);
            uint2 va = h8[(size_t)sa * LPR + fid];
            uint2 vb = h8[(size_t)sb * LPR + fid];
            uint2 vc = h8[(size_t)sc * LPR + fid];
            uint2 vd = h8[(size_t)sd * LPR + fid];
            macc8f8(acc, va, ca);
            macc8f8(acc, vb, cb);
            macc8f8(acc, vc, cc);
            macc8f8(acc, vd, cd);
        }
        for (; j + 2 * RPS <= cnt; j += 2 * RPS) {
            int ja = j + sub, jb = j + RPS + sub;
            int sa = __shfl(sv, ja); float ca = __shfl(dv, ja);
            int sb = __shfl(sv, jb); float cb = __shfl(dv, jb);
            uint2 va = h8[(size_t)sa * LPR + fid];
            uint2 vb = h8[(size_t)sb * LPR + fid];
            macc8f8(acc, va, ca);
            macc8f8(acc, vb, cb);
        }
        for (; j < cnt; j += RPS) {
            int jj = j + sub;
            int jc = min(jj, cnt - 1);
            int s = __shfl(sv, jc);
            float c = __shfl(dv, jc);
            if (jj >= cnt) c = 0.f;
            uint2 v = h8[(size_t)s * LPR + fid];
            macc8f8(acc, v, c);
        }
    }
#pragma unroll
    for (int m = LPR; m < 64; m <<= 1) {
#pragma unroll
        for (int i = 0; i < 8; ++i) acc[i] += __shfl_xor(acc[i], m);
    }
}

// --- pack W[K][NC] fp32 -> bf16 MFMA B-frag order (device body) ---
template <int K, int NC>
__device__ __forceinline__ void wprep_body(int bid, const float* __restrict__ W,
                                           unsigned short* __restrict__ Wf) {
    constexpr int CT = NC / 32, KT = K / 16;
    int idx = bid * 256 + threadIdx.x;
    if (idx >= KT * CT * 64) return;
    int l = idx & 63;
    int fi = idx >> 6;
    int ct = fi % CT, kt = fi / CT;
    int n = ct * 32 + (l & 31);
    int k0 = kt * 16 + 8 * (l >> 5);
    unsigned short v[8];
#pragma unroll
    for (int j = 0; j < 8; ++j) v[j] = f2bf(W[(size_t)(k0 + j) * NC + n]);
    uint4 o;
    o.x = (unsigned)v[0] | ((unsigned)v[1] << 16);
    o.y = (unsigned)v[2] | ((unsigned)v[3] << 16);
    o.z = (unsigned)v[4] | ((unsigned)v[5] << 16);
    o.w = (unsigned)v[6] | ((unsigned)v[7] << 16);
    *(uint4*)&Wf[(size_t)idx * 8] = o;
}

// --- fused A: bucket histogram (blocks < EB) || wprep1 || wprep2 ---
__global__ __launch_bounds__(256) void fusedA_kernel(const int* __restrict__ dst,
                                                     int* __restrict__ bcount, int E, int EB,
                                                     const float* __restrict__ W1,
                                                     unsigned short* __restrict__ Wp1,
                                                     const float* __restrict__ W2,
                                                     unsigned short* __restrict__ Wp2) {
    __shared__ int h[256];
    int b = blockIdx.x;
    int t = threadIdx.x;
    if (b < EB) {
        h[t] = 0;
        __syncthreads();
        int base = b * 4096;
#pragma unroll
        for (int i = 0; i < 16; ++i) {
            int e = base + t + i * 256;
            if (e < E) atomicAdd(&h[dst[e] >> 9], 1);
        }
        __syncthreads();
        if (h[t] > 0) atomicAdd(&bcount[t], h[t]);
    } else if (b < EB + 8) {
        wprep_body<128, 128>(b - EB, W1, Wp1);
    } else {
        wprep_body<128, 64>(b - EB - 8, W2, Wp2);
    }
}

// --- A2: stage packed (src | local_dst<<17) into bucket windows. ---
__global__ __launch_bounds__(256) void bucket_scatter_kernel(const int* __restrict__ src,
                                                             const int* __restrict__ dst,
                                                             const int* __restrict__ bcount,
                                                             int* __restrict__ bfill,
                                                             unsigned int* __restrict__ stage,
                                                             int E) {
    __shared__ int sc[256];
    __shared__ int hist[256];
    __shared__ int abase[256];
    int t = threadIdx.x;
    int bc = bcount[t];
    sc[t] = bc;
    __syncthreads();
    for (int off = 1; off < 256; off <<= 1) {
        int tmp = 0;
        if (t >= off) tmp = sc[t - off];
        __syncthreads();
        sc[t] += tmp;
        __syncthreads();
    }
    int bstart_t = sc[t] - bc;   // exclusive prefix
    hist[t] = 0;
    __syncthreads();
    int base = blockIdx.x * 4096;
    int dcache[16];
#pragma unroll
    for (int i = 0; i < 16; ++i) {
        int e = base + t + i * 256;
        dcache[i] = (e < E) ? dst[e] : -1;
        if (dcache[i] >= 0) atomicAdd(&hist[dcache[i] >> 9], 1);
    }
    __syncthreads();
    if (hist[t] > 0) {
        int r = atomicAdd(&bfill[t], hist[t]);
        abase[t] = bstart_t + r;
    }
    __syncthreads();
    hist[t] = 0;
    __syncthreads();
#pragma unroll
    for (int i = 0; i < 16; ++i) {
        int e = base + t + i * 256;
        int d = dcache[i];
        if (d >= 0) {
            int b = d >> 9;
            int slot = atomicAdd(&hist[b], 1);
            stage[abase[b] + slot] = (unsigned)src[e] | ((unsigned)(d & 511) << 17);
        }
    }
}

// --- B: per-bucket CSR finalize (2nd pass hybrid LDS-staged) ---
#define SCAP 14336   // 56 KB LDS edge cache per bucket
__device__ __forceinline__ void csr_build_body(int b, const unsigned int* __restrict__ stage,
                                               const int* __restrict__ bcount,
                                               int* __restrict__ rowstart,
                                               float* __restrict__ dis,
                                               int* __restrict__ csr_src,
                                               int N, int NB, int E) {
    __shared__ int sc[256];
    __shared__ int cnt[512];
    __shared__ int ofs[512];
    __shared__ int psum[256];
    __shared__ unsigned int sedge[SCAP];
    int t = threadIdx.x;
    int bc = bcount[t];
    sc[t] = bc;
    __syncthreads();
    for (int off = 1; off < 256; off <<= 1) {
        int tmp = 0;
        if (t >= off) tmp = sc[t - off];
        __syncthreads();
        sc[t] += tmp;
        __syncthreads();
    }
    int ee = sc[b];              // inclusive prefix at b
    int eb = ee - bcount[b];
    if (b == NB - 1 && t == 0) rowstart[N] = E;
    int node0 = b << 9;
    int nb = min(512, N - node0);
    cnt[t] = 0;
    cnt[t + 256] = 0;
    __syncthreads();
    for (int e = eb + t; e < ee; e += 256) {
        unsigned w = stage[e];
        int le = e - eb;
        if (le < SCAP) sedge[le] = w;
        atomicAdd(&cnt[w >> 17], 1);
    }
    __syncthreads();
    int a = cnt[2 * t], c = cnt[2 * t + 1];
    int ps = a + c;
    psum[t] = ps;
    __syncthreads();
    for (int off = 1; off < 256; off <<= 1) {
        int tmp = 0;
        if (t >= off) tmp = psum[t - off];
        __syncthreads();
        psum[t] += tmp;
        __syncthreads();
    }
    int ex = psum[t] - ps;
    ofs[2 * t] = ex;
    ofs[2 * t + 1] = ex + a;
    if (2 * t < nb) {
        rowstart[node0 + 2 * t] = eb + ex;
        dis[node0 + 2 * t] = rsqrtf(1.f + (float)a);
    }
    if (2 * t + 1 < nb) {
        rowstart[node0 + 2 * t + 1] = eb + ex + a;
        dis[node0 + 2 * t + 1] = rsqrtf(1.f + (float)c);
    }
    __syncthreads();
    for (int e = eb + t; e < ee; e += 256) {
        int le = e - eb;
        unsigned w = (le < SCAP) ? sedge[le] : stage[e];
        int l = w >> 17;
        int slot = atomicAdd(&ofs[l], 1);
        csr_src[eb + slot] = (int)(w & 0x1FFFFu);
    }
}

// --- MFMA GEMM device body (layer 1): C[M][NC] fp8 = A[M][K] @ Wf ---
template <int K, int NC, bool IN_F32>
__device__ __forceinline__ void gemm_body(int gb, const void* __restrict__ Av,
                                          const unsigned short* __restrict__ Wf,
                                          unsigned char* __restrict__ C, int M) {
    constexpr int KT = K / 16, CT = NC / 32;
    int wid = gb * 4 + (int)(threadIdx.x >> 6);
    int lane = threadIdx.x & 63;
    int row0 = wid * 32;
    if (row0 >= M) return;

    bfrag B[KT][CT];
#pragma unroll
    for (int kt = 0; kt < KT; ++kt)
#pragma unroll
        for (int ct = 0; ct < CT; ++ct)
            B[kt][ct] = *(const bfrag*)&Wf[(size_t)((kt * CT + ct) * 64 + lane) * 8];

    f32x16 acc[CT];
#pragma unroll
    for (int ct = 0; ct < CT; ++ct)
#pragma unroll
        for (int i = 0; i < 16; ++i) acc[ct][i] = 0.f;

    int r = row0 + (lane & 31);
    if (r >= M) r = M - 1;
#pragma unroll
    for (int kt = 0; kt < KT; ++kt) {
        bfrag a;
        if (IN_F32) {
            const float* Arow = &((const float*)Av)[(size_t)r * K + 8 * (lane >> 5)];
            float4 v0 = *(const float4*)&Arow[kt * 16];
            float4 v1 = *(const float4*)&Arow[kt * 16 + 4];
            a[0] = (short)f2bf(v0.x); a[1] = (short)f2bf(v0.y);
            a[2] = (short)f2bf(v0.z); a[3] = (short)f2bf(v0.w);
            a[4] = (short)f2bf(v1.x); a[5] = (short)f2bf(v1.y);
            a[6] = (short)f2bf(v1.z); a[7] = (short)f2bf(v1.w);
        } else {
            const unsigned short* Arow =
                &((const unsigned short*)Av)[(size_t)r * K + 8 * (lane >> 5)];
            a = *(const bfrag*)&Arow[kt * 16];
        }
#pragma unroll
        for (int ct = 0; ct < CT; ++ct)
            acc[ct] = __builtin_amdgcn_mfma_f32_32x32x16_bf16(a, B[kt][ct], acc[ct], 0, 0, 0);
    }

    // C/D layout: col = lane&31, row = (reg&3) + 8*(reg>>2) + 4*(lane>>5)
    int colb = lane & 31;
    int rowq = 4 * (lane >> 5);
#pragma unroll
    for (int ct = 0; ct < CT; ++ct) {
        int col = ct * 32 + colb;
#pragma unroll
        for (int rg = 0; rg < 16; ++rg) {
            int row = row0 + (rg & 3) + 8 * (rg >> 2) + rowq;
            if (row < M) C[(size_t)row * NC + col] = f2fp8(acc[ct][rg]);
        }
    }
}

// --- fused B: csr_build (blocks < NB) || gemm1 (x @ W1 -> fp8) ---
__global__ __launch_bounds__(256) void fusedB_kernel(const unsigned int* __restrict__ stage,
                                                     const int* __restrict__ bcount,
                                                     int* __restrict__ rowstart,
                                                     float* __restrict__ dis,
                                                     int* __restrict__ csr_src,
                                                     int N, int NB, int E,
                                                     const float* __restrict__ x,
                                                     const unsigned short* __restrict__ Wp1,
                                                     unsigned char* __restrict__ hf8) {
    int b = blockIdx.x;
    if (b < NB) {
        csr_build_body(b, stage, bcount, rowstart, dis, csr_src, N, NB, E);
    } else {
        gemm_body<128, 128, true>(b - NB, x, Wp1, hf8, N);
    }
}

// --- agg128g: layer-1 aggregate + fused gemm2 (h1 @ W2 -> gf8) ---
//     1024 thr = 16 waves x 2 nodes = 32 node rows; LDS h1 tile; waves 0,1
//     run 32x32x16 MFMA (proven layout, existing Wp2 pack).
__global__ __launch_bounds__(1024) void agg128g_kernel(const unsigned char* __restrict__ h,
                                                       const float* __restrict__ dis,
                                                       const int* __restrict__ rowstart,
                                                       const int* __restrict__ csr_src,
                                                       const float* __restrict__ bias,
                                                       const unsigned short* __restrict__ Wp2,
                                                       unsigned char* __restrict__ gf8,
                                                       int N) {
    __shared__ unsigned short lds_h1[32 * 128];   // 8 KB
    int w = threadIdx.x >> 6;
    int lane = threadIdx.x & 63;
    int node0 = blockIdx.x * 32;
    const uint2* h8 = (const uint2*)h;
    int fid = lane & 15;
    int sub = lane >> 4;
#pragma unroll 1
    for (int j = 0; j < 2; ++j) {
        int lrow = w * 2 + j;
        int n = node0 + lrow;
        if (n < N) {
            float d = dis[n];
            float acc[8];
            gather_node<128>(h8, dis, rowstart, csr_src, n, lane, d, acc);
            if (sub == 0) {
                const float4 bv0 = *(const float4*)&bias[fid * 8 + 0];
                const float4 bv1 = *(const float4*)&bias[fid * 8 + 4];
                float r[8];
                r[0] = fmaxf(acc[0] * d + bv0.x, 0.f);
                r[1] = fmaxf(acc[1] * d + bv0.y, 0.f);
                r[2] = fmaxf(acc[2] * d + bv0.z, 0.f);
                r[3] = fmaxf(acc[3] * d + bv0.w, 0.f);
                r[4] = fmaxf(acc[4] * d + bv1.x, 0.f);
                r[5] = fmaxf(acc[5] * d + bv1.y, 0.f);
                r[6] = fmaxf(acc[6] * d + bv1.z, 0.f);
                r[7] = fmaxf(acc[7] * d + bv1.w, 0.f);
                uint4 o;
                o.x = (unsigned)f2bf(r[0]) | ((unsigned)f2bf(r[1]) << 16);
                o.y = (unsigned)f2bf(r[2]) | ((unsigned)f2bf(r[3]) << 16);
                o.z = (unsigned)f2bf(r[4]) | ((unsigned)f2bf(r[5]) << 16);
                o.w = (unsigned)f2bf(r[6]) | ((unsigned)f2bf(r[7]) << 16);
                *(uint4*)&lds_h1[lrow * 128 + fid * 8] = o;
            }
        } else if (sub == 0) {
            uint4 z = make_uint4(0, 0, 0, 0);
            *(uint4*)&lds_h1[lrow * 128 + fid * 8] = z;
        }
    }
    __syncthreads();
    if (w < 2) {
        int ct = w;          // col tile: cols ct*32..ct*32+31 of 64
        f32x16 acc;
#pragma unroll
        for (int i = 0; i < 16; ++i) acc[i] = 0.f;
#pragma unroll 1
        for (int kt = 0; kt < 8; ++kt) {
            bfrag a = *(const bfrag*)&lds_h1[(lane & 31) * 128 + kt * 16 + 8 * (lane >> 5)];
            bfrag Bf = *(const bfrag*)&Wp2[(size_t)((kt * 2 + ct) * 64 + lane) * 8];
            acc = __builtin_amdgcn_mfma_f32_32x32x16_bf16(a, Bf, acc, 0, 0, 0);
        }
        int colb = lane & 31;
        int rowq = 4 * (lane >> 5);
        int col = ct * 32 + colb;
#pragma unroll
        for (int rg = 0; rg < 16; ++rg) {
            int lrow = (rg & 3) + 8 * (rg >> 2) + rowq;
            int node = node0 + lrow;
            if (node < N) gf8[(size_t)node * 64 + col] = f2fp8(acc[rg]);
        }
    }
}

// --- agg64p: layer-2 aggregate + fused mean-pool accumulation ---
//     512 thr = 8 waves x 1 node; LDS f32 tile; 64 threads run-reduce the
//     8 (batch-sorted) rows and atomicAdd per graph run into gsum.
__global__ __launch_bounds__(512) void agg64p_kernel(const unsigned char* __restrict__ g,
                                                     const float* __restrict__ dis,
                                                     const int* __restrict__ rowstart,
                                                     const int* __restrict__ csr_src,
                                                     const float* __restrict__ bias,
                                                     const int* __restrict__ batch,
                                                     float* __restrict__ gsum,
                                                     int* __restrict__ gcnt,
                                                     int N) {
    __shared__ float tile[8][64];   // 2 KB
    __shared__ int sb[8];
    int w = threadIdx.x >> 6;
    int lane = threadIdx.x & 63;
    int n = blockIdx.x * 8 + w;
    const uint2* h8 = (const uint2*)g;
    int fid = lane & 7;
    int sub = lane >> 3;
    if (threadIdx.x < 8) {
        int nn = blockIdx.x * 8 + (int)threadIdx.x;
        sb[threadIdx.x] = (nn < N) ? batch[nn] : -1;
    }
    if (n < N) {
        float d = dis[n];
        float acc[8];
        gather_node<64>(h8, dis, rowstart, csr_src, n, lane, d, acc);
        if (sub == 0) {
            const float4 bv0 = *(const float4*)&bias[fid * 8 + 0];
            const float4 bv1 = *(const float4*)&bias[fid * 8 + 4];
            float r[8];
            r[0] = fmaxf(acc[0] * d + bv0.x, 0.f);
            r[1] = fmaxf(acc[1] * d + bv0.y, 0.f);
            r[2] = fmaxf(acc[2] * d + bv0.z, 0.f);
            r[3] = fmaxf(acc[3] * d + bv0.w, 0.f);
            r[4] = fmaxf(acc[4] * d + bv1.x, 0.f);
            r[5] = fmaxf(acc[5] * d + bv1.y, 0.f);
            r[6] = fmaxf(acc[6] * d + bv1.z, 0.f);
            r[7] = fmaxf(acc[7] * d + bv1.w, 0.f);
#pragma unroll
            for (int i = 0; i < 8; ++i)
                tile[w][fid * 8 + i] = bf2f(f2bf(r[i]));   // bf16-rounded (as before)
        }
    } else if (sub == 0) {
#pragma unroll
        for (int i = 0; i < 8; ++i) tile[w][fid * 8 + i] = 0.f;
    }
    __syncthreads();
    int t = threadIdx.x;
    if (t < 64) {
        float a = 0.f;
        int gcur = -1;
#pragma unroll
        for (int r2 = 0; r2 < 8; ++r2) {
            int g2 = sb[r2];
            if (g2 < 0) continue;
            if (g2 != gcur) {
                if (gcur >= 0) atomicAdd(&gsum[gcur * 64 + t], a);
                a = 0.f;
                gcur = g2;
            }
            a += tile[r2][t];
        }
        if (gcur >= 0) atomicAdd(&gsum[gcur * 64 + t], a);
    } else if (t < 72) {
        int r2 = t - 64;
        if (sb[r2] >= 0) atomicAdd(&gcnt[sb[r2]], 1);
    }
}

// --- head: ge = pooled_h2 @ Wf1 + bf1 ; ic = ge @ Wf2 + bf2 ---
__global__ __launch_bounds__(128) void head_kernel(const float* __restrict__ gsum,
                                                   const int* __restrict__ gcnt,
                                                   const float* __restrict__ Wf1,
                                                   const float* __restrict__ bf1,
                                                   const float* __restrict__ Wf2,
                                                   const float* __restrict__ bf2,
                                                   float* __restrict__ out) {
    __shared__ float ph[64];
    __shared__ float red0[128], red1[128];
    int g = blockIdx.x, f = threadIdx.x;
    if (f < 64) ph[f] = gsum[g * 64 + f] / (float)max(gcnt[g], 1);
    __syncthreads();
    float ge = bf1[f];
#pragma unroll 8
    for (int k = 0; k < 64; ++k) ge += ph[k] * Wf1[k * 128 + f];
    out[g * 128 + f] = ge;
    red0[f] = ge * Wf2[f * 2 + 0];
    red1[f] = ge * Wf2[f * 2 + 1];
    __syncthreads();
    for (int off = 64; off > 0; off >>= 1) {
        if (f < off) { red0[f] += red0[f + off]; red1[f] += red1[f + off]; }
        __syncthreads();
    }
    if (f == 0) {
        out[8192 + 1 + g * 2 + 0] = red0[0] + bf2[0];
        out[8192 + 1 + g * 2 + 1] = red1[0] + bf2[1];
        if (g == 0) out[8192] = 0.f;
    }
}

extern "C" void kernel_launch(void* const* d_in, const int* in_sizes, int n_in,
                              void* d_out, int out_size, void* d_ws, size_t ws_size,
                              hipStream_t stream) {
    const float* x   = (const float*)d_in[0];
    const float* W1  = (const float*)d_in[1];
    const float* b1  = (const float*)d_in[2];
    const float* W2  = (const float*)d_in[3];
    const float* b2  = (const float*)d_in[4];
    const float* Wf1 = (const float*)d_in[5];
    const float* bf1 = (const float*)d_in[6];
    const float* Wf2 = (const float*)d_in[7];
    const float* bf2 = (const float*)d_in[8];
    const int* edge  = (const int*)d_in[9];
    const int* batch = (const int*)d_in[10];

    const int N = in_sizes[10];      // 100000
    const int E = in_sizes[9] / 2;   // 3200000
    const int* srcA = edge;
    const int* dstA = edge + E;
    float* out = (float*)d_out;

    const int NB = (N + 511) >> 9;   // dst buckets of 512 nodes

    char* p = (char*)d_ws;
    auto alloc = [&](size_t bytes) {
        char* r = p;
        p += (bytes + 255) & ~(size_t)255;
        return r;
    };
    float* gsum     = (float*)alloc(64 * 64 * 4);
    int*   gcnt     = (int*)alloc(64 * 4);
    int*   bcount   = (int*)alloc(256 * 4);
    int*   bfill    = (int*)alloc(256 * 4);
    size_t zbytes   = (size_t)(p - (char*)d_ws);
    float* dis      = (float*)alloc((size_t)N * 4);
    int*   rowstart = (int*)alloc((size_t)(N + 1) * 4);
    unsigned short* Wp1 = (unsigned short*)alloc(8 * 4 * 64 * 8 * 2);  // 32 KB
    unsigned short* Wp2 = (unsigned short*)alloc(8 * 2 * 64 * 8 * 2);  // 16 KB
    unsigned int* stage = (unsigned int*)alloc((size_t)E * 4);
    int*   csr_src  = (int*)alloc((size_t)E * 4);
    unsigned char* hf8  = (unsigned char*)alloc((size_t)N * 128);  // layer-1 h (fp8)
    unsigned char* gf8  = (unsigned char*)alloc((size_t)N * 64);   // layer-2 g (fp8)

    (void)hipMemsetAsync(d_ws, 0, zbytes, stream);

    const int EB = (E + 4095) / 4096;
    const int GB = (N + 127) / 128;   // 4 waves x 32 rows per block
    // hist || weight-prep (independent, both low-VGPR)
    fusedA_kernel<<<EB + 12, 256, 0, stream>>>(dstA, bcount, E, EB, W1, Wp1, W2, Wp2);
    bucket_scatter_kernel<<<EB, 256, 0, stream>>>(srcA, dstA, bcount, bfill, stage, E);
    // csr_build || gemm1 (independent; build grid 196 < 256 CUs)
    fusedB_kernel<<<NB + GB, 256, 0, stream>>>(stage, bcount, rowstart, dis, csr_src,
                                               N, NB, E, x, Wp1, hf8);
    // layer-1 aggregate + fused gemm2 -> gf8
    agg128g_kernel<<<(N + 31) / 32, 1024, 0, stream>>>(hf8, dis, rowstart, csr_src,
                                                       b1, Wp2, gf8, N);
    // layer-2 aggregate + fused pool/count -> gsum, gcnt
    agg64p_kernel<<<(N + 7) / 8, 512, 0, stream>>>(gf8, dis, rowstart, csr_src,
                                                   b2, batch, gsum, gcnt, N);
    head_kernel<<<64, 128, 0, stream>>>(gsum, gcnt, Wf1, bf1, Wf2, bf2, out);
}

// Round 12
// 379.445 us; speedup vs baseline: 2.9782x; 2.9782x over previous
//
#include <hip/hip_runtime.h>

// ---------------------------------------------------------------------------
// GCN forward. Weights fp32->bf16 MFMA, activations: gather buffers in FP8
// (e4m3, HW cvt), GEMM inputs/pool in bf16, accumulation fp32.
// CSR: bucketed radix (dst>>9, 512 nodes/bucket), contiguous per-node lists.
// Aggregate: R4-proven sub-wave gather, uint2 (8B) fp8 rows (73us form).
// R10-proven structure (380.8us): fusedA = hist||wprep, fusedB =
// csr_build||gemm1, standalone gemm2, poolcount, head. R11's epilogue-fusion
// REVERTED: barrier-coupled mega-blocks + same-address atomic storms
// serialized agg64p to 823us (VALUBusy 4%).
// ---------------------------------------------------------------------------

typedef __attribute__((ext_vector_type(8))) short bfrag;     // 8 bf16 = 4 VGPR
typedef __attribute__((ext_vector_type(16))) float f32x16;   // MFMA C/D
typedef __attribute__((ext_vector_type(2))) float floatx2;

__device__ __forceinline__ unsigned short f2bf(float f) {
    unsigned int u = __builtin_bit_cast(unsigned int, f);
    u = (u + 0x7FFFu + ((u >> 16) & 1u)) >> 16;
    return (unsigned short)u;
}
__device__ __forceinline__ float bf2f(unsigned int lo16) {
    unsigned int v = lo16 << 16;
    return __builtin_bit_cast(float, v);
}
__device__ __forceinline__ unsigned char f2fp8(float f) {
    return (unsigned char)(__builtin_amdgcn_cvt_pk_fp8_f32(f, f, 0, false) & 0xFF);
}
// 8 fp8 (uint2) -> fp32, acc += f * c   (HW packed converts, 2 vals/op)
__device__ __forceinline__ void macc8f8(float* acc, const uint2& v, float c) {
    floatx2 f0 = __builtin_amdgcn_cvt_pk_f32_fp8((int)v.x, false);
    floatx2 f1 = __builtin_amdgcn_cvt_pk_f32_fp8((int)v.x, true);
    floatx2 f2 = __builtin_amdgcn_cvt_pk_f32_fp8((int)v.y, false);
    floatx2 f3 = __builtin_amdgcn_cvt_pk_f32_fp8((int)v.y, true);
    acc[0] += f0.x * c; acc[1] += f0.y * c;
    acc[2] += f1.x * c; acc[3] += f1.y * c;
    acc[4] += f2.x * c; acc[5] += f2.y * c;
    acc[6] += f3.x * c; acc[7] += f3.y * c;
}

// --- pack W[K][NC] fp32 -> bf16 MFMA B-frag order (device body) ---
template <int K, int NC>
__device__ __forceinline__ void wprep_body(int bid, const float* __restrict__ W,
                                           unsigned short* __restrict__ Wf) {
    constexpr int CT = NC / 32, KT = K / 16;
    int idx = bid * 256 + threadIdx.x;
    if (idx >= KT * CT * 64) return;
    int l = idx & 63;
    int fi = idx >> 6;
    int ct = fi % CT, kt = fi / CT;
    int n = ct * 32 + (l & 31);
    int k0 = kt * 16 + 8 * (l >> 5);
    unsigned short v[8];
#pragma unroll
    for (int j = 0; j < 8; ++j) v[j] = f2bf(W[(size_t)(k0 + j) * NC + n]);
    uint4 o;
    o.x = (unsigned)v[0] | ((unsigned)v[1] << 16);
    o.y = (unsigned)v[2] | ((unsigned)v[3] << 16);
    o.z = (unsigned)v[4] | ((unsigned)v[5] << 16);
    o.w = (unsigned)v[6] | ((unsigned)v[7] << 16);
    *(uint4*)&Wf[(size_t)idx * 8] = o;
}

// --- fused A: bucket histogram (blocks < EB) || wprep1 || wprep2 ---
__global__ __launch_bounds__(256) void fusedA_kernel(const int* __restrict__ dst,
                                                     int* __restrict__ bcount, int E, int EB,
                                                     const float* __restrict__ W1,
                                                     unsigned short* __restrict__ Wp1,
                                                     const float* __restrict__ W2,
                                                     unsigned short* __restrict__ Wp2) {
    __shared__ int h[256];
    int b = blockIdx.x;
    int t = threadIdx.x;
    if (b < EB) {
        h[t] = 0;
        __syncthreads();
        int base = b * 4096;
#pragma unroll
        for (int i = 0; i < 16; ++i) {
            int e = base + t + i * 256;
            if (e < E) atomicAdd(&h[dst[e] >> 9], 1);
        }
        __syncthreads();
        if (h[t] > 0) atomicAdd(&bcount[t], h[t]);
    } else if (b < EB + 8) {
        wprep_body<128, 128>(b - EB, W1, Wp1);
    } else {
        wprep_body<128, 64>(b - EB - 8, W2, Wp2);
    }
}

// --- A2: stage packed (src | local_dst<<17) into bucket windows.
//     bstart via redundant block-local scan of bcount; dst reg-cached. ---
__global__ __launch_bounds__(256) void bucket_scatter_kernel(const int* __restrict__ src,
                                                             const int* __restrict__ dst,
                                                             const int* __restrict__ bcount,
                                                             int* __restrict__ bfill,
                                                             unsigned int* __restrict__ stage,
                                                             int E) {
    __shared__ int sc[256];
    __shared__ int hist[256];
    __shared__ int abase[256];
    int t = threadIdx.x;
    int bc = bcount[t];
    sc[t] = bc;
    __syncthreads();
    for (int off = 1; off < 256; off <<= 1) {
        int tmp = 0;
        if (t >= off) tmp = sc[t - off];
        __syncthreads();
        sc[t] += tmp;
        __syncthreads();
    }
    int bstart_t = sc[t] - bc;   // exclusive prefix
    hist[t] = 0;
    __syncthreads();
    int base = blockIdx.x * 4096;
    int dcache[16];
#pragma unroll
    for (int i = 0; i < 16; ++i) {
        int e = base + t + i * 256;
        dcache[i] = (e < E) ? dst[e] : -1;
        if (dcache[i] >= 0) atomicAdd(&hist[dcache[i] >> 9], 1);
    }
    __syncthreads();
    if (hist[t] > 0) {
        int r = atomicAdd(&bfill[t], hist[t]);
        abase[t] = bstart_t + r;
    }
    __syncthreads();
    hist[t] = 0;
    __syncthreads();
#pragma unroll
    for (int i = 0; i < 16; ++i) {
        int e = base + t + i * 256;
        int d = dcache[i];
        if (d >= 0) {
            int b = d >> 9;
            int slot = atomicAdd(&hist[b], 1);
            stage[abase[b] + slot] = (unsigned)src[e] | ((unsigned)(d & 511) << 17);
        }
    }
}

// --- B: per-bucket CSR finalize (device body; 2nd pass hybrid LDS-staged) ---
#define SCAP 14336   // 56 KB LDS edge cache per bucket
__device__ __forceinline__ void csr_build_body(int b, const unsigned int* __restrict__ stage,
                                               const int* __restrict__ bcount,
                                               int* __restrict__ rowstart,
                                               float* __restrict__ dis,
                                               int* __restrict__ csr_src,
                                               int N, int NB, int E) {
    __shared__ int sc[256];
    __shared__ int cnt[512];
    __shared__ int ofs[512];
    __shared__ int psum[256];
    __shared__ unsigned int sedge[SCAP];
    int t = threadIdx.x;
    int bc = bcount[t];
    sc[t] = bc;
    __syncthreads();
    for (int off = 1; off < 256; off <<= 1) {
        int tmp = 0;
        if (t >= off) tmp = sc[t - off];
        __syncthreads();
        sc[t] += tmp;
        __syncthreads();
    }
    int ee = sc[b];              // inclusive prefix at b
    int eb = ee - bcount[b];
    if (b == NB - 1 && t == 0) rowstart[N] = E;
    int node0 = b << 9;
    int nb = min(512, N - node0);
    cnt[t] = 0;
    cnt[t + 256] = 0;
    __syncthreads();
    for (int e = eb + t; e < ee; e += 256) {
        unsigned w = stage[e];
        int le = e - eb;
        if (le < SCAP) sedge[le] = w;
        atomicAdd(&cnt[w >> 17], 1);
    }
    __syncthreads();
    int a = cnt[2 * t], c = cnt[2 * t + 1];
    int ps = a + c;
    psum[t] = ps;
    __syncthreads();
    for (int off = 1; off < 256; off <<= 1) {
        int tmp = 0;
        if (t >= off) tmp = psum[t - off];
        __syncthreads();
        psum[t] += tmp;
        __syncthreads();
    }
    int ex = psum[t] - ps;
    ofs[2 * t] = ex;
    ofs[2 * t + 1] = ex + a;
    if (2 * t < nb) {
        rowstart[node0 + 2 * t] = eb + ex;
        dis[node0 + 2 * t] = rsqrtf(1.f + (float)a);
    }
    if (2 * t + 1 < nb) {
        rowstart[node0 + 2 * t + 1] = eb + ex + a;
        dis[node0 + 2 * t + 1] = rsqrtf(1.f + (float)c);
    }
    __syncthreads();
    for (int e = eb + t; e < ee; e += 256) {
        int le = e - eb;
        unsigned w = (le < SCAP) ? sedge[le] : stage[e];
        int l = w >> 17;
        int slot = atomicAdd(&ofs[l], 1);
        csr_src[eb + slot] = (int)(w & 0x1FFFFu);
    }
}

// --- MFMA GEMM device body: C[M][NC] = A[M][K] @ Wf(frag-packed bf16) ---
template <int K, int NC, bool IN_F32>
__device__ __forceinline__ void gemm_body(int gb, const void* __restrict__ Av,
                                          const unsigned short* __restrict__ Wf,
                                          unsigned char* __restrict__ C, int M) {
    constexpr int KT = K / 16, CT = NC / 32;
    int wid = gb * 4 + (int)(threadIdx.x >> 6);
    int lane = threadIdx.x & 63;
    int row0 = wid * 32;
    if (row0 >= M) return;

    bfrag B[KT][CT];
#pragma unroll
    for (int kt = 0; kt < KT; ++kt)
#pragma unroll
        for (int ct = 0; ct < CT; ++ct)
            B[kt][ct] = *(const bfrag*)&Wf[(size_t)((kt * CT + ct) * 64 + lane) * 8];

    f32x16 acc[CT];
#pragma unroll
    for (int ct = 0; ct < CT; ++ct)
#pragma unroll
        for (int i = 0; i < 16; ++i) acc[ct][i] = 0.f;

    int r = row0 + (lane & 31);
    if (r >= M) r = M - 1;
#pragma unroll
    for (int kt = 0; kt < KT; ++kt) {
        bfrag a;
        if (IN_F32) {
            const float* Arow = &((const float*)Av)[(size_t)r * K + 8 * (lane >> 5)];
            float4 v0 = *(const float4*)&Arow[kt * 16];
            float4 v1 = *(const float4*)&Arow[kt * 16 + 4];
            a[0] = (short)f2bf(v0.x); a[1] = (short)f2bf(v0.y);
            a[2] = (short)f2bf(v0.z); a[3] = (short)f2bf(v0.w);
            a[4] = (short)f2bf(v1.x); a[5] = (short)f2bf(v1.y);
            a[6] = (short)f2bf(v1.z); a[7] = (short)f2bf(v1.w);
        } else {
            const unsigned short* Arow =
                &((const unsigned short*)Av)[(size_t)r * K + 8 * (lane >> 5)];
            a = *(const bfrag*)&Arow[kt * 16];
        }
#pragma unroll
        for (int ct = 0; ct < CT; ++ct)
            acc[ct] = __builtin_amdgcn_mfma_f32_32x32x16_bf16(a, B[kt][ct], acc[ct], 0, 0, 0);
    }

    // C/D layout: col = lane&31, row = (reg&3) + 8*(reg>>2) + 4*(lane>>5)
    int colb = lane & 31;
    int rowq = 4 * (lane >> 5);
#pragma unroll
    for (int ct = 0; ct < CT; ++ct) {
        int col = ct * 32 + colb;
#pragma unroll
        for (int rg = 0; rg < 16; ++rg) {
            int row = row0 + (rg & 3) + 8 * (rg >> 2) + rowq;
            if (row < M) C[(size_t)row * NC + col] = f2fp8(acc[ct][rg]);
        }
    }
}

// --- fused B: csr_build (blocks < NB) || gemm1 (x @ W1 -> fp8) ---
__global__ __launch_bounds__(256) void fusedB_kernel(const unsigned int* __restrict__ stage,
                                                     const int* __restrict__ bcount,
                                                     int* __restrict__ rowstart,
                                                     float* __restrict__ dis,
                                                     int* __restrict__ csr_src,
                                                     int N, int NB, int E,
                                                     const float* __restrict__ x,
                                                     const unsigned short* __restrict__ Wp1,
                                                     unsigned char* __restrict__ hf8) {
    int b = blockIdx.x;
    if (b < NB) {
        csr_build_body(b, stage, bcount, rowstart, dis, csr_src, N, NB, E);
    } else {
        gemm_body<128, 128, true>(b - NB, x, Wp1, hf8, N);
    }
}

// --- standalone GEMM (layer 2) ---
template <int K, int NC, bool IN_F32>
__global__ __launch_bounds__(256) void gemm_mfma_kernel(const void* __restrict__ Av,
                                                        const unsigned short* __restrict__ Wf,
                                                        unsigned char* __restrict__ C,
                                                        int M) {
    gemm_body<K, NC, IN_F32>(blockIdx.x, Av, Wf, C, M);
}

// --- wave-per-node gather aggregation (R4-proven form): fp8 rows (8B/lane),
//     fp32 accum, bf16 out: out = relu(d*(sum dis_s*h_s + d*h_n) + bias)
template <int NC>
__global__ __launch_bounds__(256) void aggregate_kernel(const unsigned char* __restrict__ h,
                                                        const float* __restrict__ dis,
                                                        const int* __restrict__ rowstart,
                                                        const int* __restrict__ csr_src,
                                                        const float* __restrict__ bias,
                                                        unsigned short* __restrict__ out,
                                                        int N) {
    constexpr int LPR = NC / 8;   // lanes per row (8B = 8 fp8 each)
    constexpr int RPS = 64 / LPR; // rows (edges) per step
    int wid = (blockIdx.x * blockDim.x + threadIdx.x) >> 6;
    int lane = threadIdx.x & 63;
    if (wid >= N) return;
    int n = wid;
    int sub = lane / LPR;
    int fid = lane % LPR;
    const uint2* h8 = (const uint2*)h;   // row = LPR uint2
    float d = dis[n];
    float acc[8];
#pragma unroll
    for (int i = 0; i < 8; ++i) acc[i] = 0.f;
    if (sub == 0) {
        uint2 hv = h8[(size_t)n * LPR + fid];
        macc8f8(acc, hv, d);
    }

    int beg = rowstart[n], end = rowstart[n + 1];
    for (int e0 = beg; e0 < end; e0 += 64) {
        int idx = e0 + lane;
        int sv = 0;
        float dv = 0.f;
        if (idx < end) {
            sv = __builtin_nontemporal_load(&csr_src[idx]);
            dv = dis[sv];
        }
        int cnt = min(64, end - e0);
        int j = 0;
        for (; j + 4 * RPS <= cnt; j += 4 * RPS) {
            int ja = j + sub, jb = j + RPS + sub, jc2 = j + 2 * RPS + sub,
                jd = j + 3 * RPS + sub;
            int sa = __shfl(sv, ja); float ca = __shfl(dv, ja);
            int sb = __shfl(sv, jb); float cb = __shfl(dv, jb);
            int sc = __shfl(sv, jc2); float cc = __shfl(dv, jc2);
            int sd = __shfl(sv, jd); float cd = __shfl(dv, jd);
            uint2 va = h8[(size_t)sa * LPR + fid];
            uint2 vb = h8[(size_t)sb * LPR + fid];
            uint2 vc = h8[(size_t)sc * LPR + fid];
            uint2 vd = h8[(size_t)sd * LPR + fid];
            macc8f8(acc, va, ca);
            macc8f8(acc, vb, cb);
            macc8f8(acc, vc, cc);
            macc8f8(acc, vd, cd);
        }
        for (; j + 2 * RPS <= cnt; j += 2 * RPS) {
            int ja = j + sub, jb = j + RPS + sub;
            int sa = __shfl(sv, ja); float ca = __shfl(dv, ja);
            int sb = __shfl(sv, jb); float cb = __shfl(dv, jb);
            uint2 va = h8[(size_t)sa * LPR + fid];
            uint2 vb = h8[(size_t)sb * LPR + fid];
            macc8f8(acc, va, ca);
            macc8f8(acc, vb, cb);
        }
        for (; j < cnt; j += RPS) {
            int jj = j + sub;
            int jc = min(jj, cnt - 1);
            int s = __shfl(sv, jc);
            float c = __shfl(dv, jc);
            if (jj >= cnt) c = 0.f;
            uint2 v = h8[(size_t)s * LPR + fid];
            macc8f8(acc, v, c);
        }
    }
#pragma unroll
    for (int m = LPR; m < 64; m <<= 1) {
#pragma unroll
        for (int i = 0; i < 8; ++i) acc[i] += __shfl_xor(acc[i], m);
    }
    if (sub == 0) {
        const float4 bv0 = *(const float4*)&bias[fid * 8 + 0];
        const float4 bv1 = *(const float4*)&bias[fid * 8 + 4];
        float r[8];
        r[0] = fmaxf(acc[0] * d + bv0.x, 0.f);
        r[1] = fmaxf(acc[1] * d + bv0.y, 0.f);
        r[2] = fmaxf(acc[2] * d + bv0.z, 0.f);
        r[3] = fmaxf(acc[3] * d + bv0.w, 0.f);
        r[4] = fmaxf(acc[4] * d + bv1.x, 0.f);
        r[5] = fmaxf(acc[5] * d + bv1.y, 0.f);
        r[6] = fmaxf(acc[6] * d + bv1.z, 0.f);
        r[7] = fmaxf(acc[7] * d + bv1.w, 0.f);
        uint4 o;
        o.x = (unsigned)f2bf(r[0]) | ((unsigned)f2bf(r[1]) << 16);
        o.y = (unsigned)f2bf(r[2]) | ((unsigned)f2bf(r[3]) << 16);
        o.z = (unsigned)f2bf(r[4]) | ((unsigned)f2bf(r[5]) << 16);
        o.w = (unsigned)f2bf(r[6]) | ((unsigned)f2bf(r[7]) << 16);
        *(uint4*)&out[(size_t)n * NC + fid * 8] = o;
    }
}

// --- fused pool+count: blocks < PB pool h2 (256thr, 4-way node stride);
//     blocks >= PB histogram batch into gcnt. (batch sorted) ---
__global__ __launch_bounds__(256) void poolcount_kernel(const unsigned short* __restrict__ h2,
                                                        const int* __restrict__ batch,
                                                        float* __restrict__ gsum,
                                                        int* __restrict__ gcnt,
                                                        int N, int PB) {
    int t = threadIdx.x;
    if ((int)blockIdx.x < PB) {
        int fid = t & 63;
        int strip = t >> 6;
        int n0 = blockIdx.x * 128;
        int nend = min(n0 + 128, N);
        int n = n0 + strip;
        if (n < nend) {
            float acc = 0.f;
            int gcur = batch[n];
            for (; n < nend; n += 4) {
                int g = batch[n];
                if (g != gcur) {
                    atomicAdd(&gsum[gcur * 64 + fid], acc);
                    acc = 0.f;
                    gcur = g;
                }
                acc += bf2f(h2[(size_t)n * 64 + fid]);
            }
            atomicAdd(&gsum[gcur * 64 + fid], acc);
        }
    } else {
        __shared__ int lc[64];
        if (t < 64) lc[t] = 0;
        __syncthreads();
        int n = ((int)blockIdx.x - PB) * 256 + t;
        if (n < N) atomicAdd(&lc[batch[n]], 1);
        __syncthreads();
        if (t < 64 && lc[t] > 0) atomicAdd(&gcnt[t], lc[t]);
    }
}

// --- head: ge = pooled_h2 @ Wf1 + bf1 ; ic = ge @ Wf2 + bf2 ---
__global__ __launch_bounds__(128) void head_kernel(const float* __restrict__ gsum,
                                                   const int* __restrict__ gcnt,
                                                   const float* __restrict__ Wf1,
                                                   const float* __restrict__ bf1,
                                                   const float* __restrict__ Wf2,
                                                   const float* __restrict__ bf2,
                                                   float* __restrict__ out) {
    __shared__ float ph[64];
    __shared__ float red0[128], red1[128];
    int g = blockIdx.x, f = threadIdx.x;
    if (f < 64) ph[f] = gsum[g * 64 + f] / (float)max(gcnt[g], 1);
    __syncthreads();
    float ge = bf1[f];
#pragma unroll 8
    for (int k = 0; k < 64; ++k) ge += ph[k] * Wf1[k * 128 + f];
    out[g * 128 + f] = ge;
    red0[f] = ge * Wf2[f * 2 + 0];
    red1[f] = ge * Wf2[f * 2 + 1];
    __syncthreads();
    for (int off = 64; off > 0; off >>= 1) {
        if (f < off) { red0[f] += red0[f + off]; red1[f] += red1[f + off]; }
        __syncthreads();
    }
    if (f == 0) {
        out[8192 + 1 + g * 2 + 0] = red0[0] + bf2[0];
        out[8192 + 1 + g * 2 + 1] = red1[0] + bf2[1];
        if (g == 0) out[8192] = 0.f;
    }
}

extern "C" void kernel_launch(void* const* d_in, const int* in_sizes, int n_in,
                              void* d_out, int out_size, void* d_ws, size_t ws_size,
                              hipStream_t stream) {
    const float* x   = (const float*)d_in[0];
    const float* W1  = (const float*)d_in[1];
    const float* b1  = (const float*)d_in[2];
    const float* W2  = (const float*)d_in[3];
    const float* b2  = (const float*)d_in[4];
    const float* Wf1 = (const float*)d_in[5];
    const float* bf1 = (const float*)d_in[6];
    const float* Wf2 = (const float*)d_in[7];
    const float* bf2 = (const float*)d_in[8];
    const int* edge  = (const int*)d_in[9];
    const int* batch = (const int*)d_in[10];

    const int N = in_sizes[10];      // 100000
    const int E = in_sizes[9] / 2;   // 3200000
    const int* srcA = edge;
    const int* dstA = edge + E;
    float* out = (float*)d_out;

    const int NB = (N + 511) >> 9;   // dst buckets of 512 nodes

    char* p = (char*)d_ws;
    auto alloc = [&](size_t bytes) {
        char* r = p;
        p += (bytes + 255) & ~(size_t)255;
        return r;
    };
    float* gsum     = (float*)alloc(64 * 64 * 4);
    int*   gcnt     = (int*)alloc(64 * 4);
    int*   bcount   = (int*)alloc(256 * 4);
    int*   bfill    = (int*)alloc(256 * 4);
    size_t zbytes   = (size_t)(p - (char*)d_ws);
    float* dis      = (float*)alloc((size_t)N * 4);
    int*   rowstart = (int*)alloc((size_t)(N + 1) * 4);
    unsigned short* Wp1 = (unsigned short*)alloc(8 * 4 * 64 * 8 * 2);  // 32 KB
    unsigned short* Wp2 = (unsigned short*)alloc(8 * 2 * 64 * 8 * 2);  // 16 KB
    unsigned int* stage = (unsigned int*)alloc((size_t)E * 4);
    int*   csr_src  = (int*)alloc((size_t)E * 4);
    unsigned char*  hf8   = (unsigned char*)alloc((size_t)N * 128);      // h then g (fp8)
    unsigned short* h1b   = (unsigned short*)alloc((size_t)N * 128 * 2); // h1 (bf16)
    unsigned short* h2b   = (unsigned short*)alloc((size_t)N * 64 * 2);  // h2 (bf16)

    (void)hipMemsetAsync(d_ws, 0, zbytes, stream);

    const int EB = (E + 4095) / 4096;
    const int GB = (N + 127) / 128;   // 4 waves x 32 rows per block
    // hist || weight-prep (independent, both low-VGPR)
    fusedA_kernel<<<EB + 12, 256, 0, stream>>>(dstA, bcount, E, EB, W1, Wp1, W2, Wp2);
    bucket_scatter_kernel<<<EB, 256, 0, stream>>>(srcA, dstA, bcount, bfill, stage, E);
    // csr_build || gemm1 (independent; build grid 196 < 256 CUs)
    fusedB_kernel<<<NB + GB, 256, 0, stream>>>(stage, bcount, rowstart, dis, csr_src,
                                               N, NB, E, x, Wp1, hf8);
    // layer 1 aggregate: h1 = relu(d*(sum+self) + b1) (bf16)
    aggregate_kernel<128><<<(N + 3) / 4, 256, 0, stream>>>(hf8, dis, rowstart, csr_src,
                                                           b1, h1b, N);
    // layer 2: g = h1@W2 (bf16 in, fp8 out) ; h2 = relu(...) (bf16)
    gemm_mfma_kernel<128, 64, false><<<GB, 256, 0, stream>>>(h1b, Wp2, hf8, N);
    aggregate_kernel<64><<<(N + 3) / 4, 256, 0, stream>>>(hf8, dis, rowstart, csr_src,
                                                          b2, h2b, N);
    // head: pool(h2)||count, then tiny GEMMs
    const int PB = (N + 127) / 128;
    const int CB = (N + 255) / 256;
    poolcount_kernel<<<PB + CB, 256, 0, stream>>>(h2b, batch, gsum, gcnt, N, PB);
    head_kernel<<<64, 128, 0, stream>>>(gsum, gcnt, Wf1, bf1, Wf2, bf2, out);
}

// Round 13
// 375.861 us; speedup vs baseline: 3.0066x; 1.0095x over previous
//
#include <hip/hip_runtime.h>

// ---------------------------------------------------------------------------
// GCN forward. Weights fp32->bf16 MFMA, activations: gather buffers in FP8
// (e4m3, HW cvt), GEMM inputs/pool in bf16, accumulation fp32.
// CSR: bucketed radix (dst>>9, 512 nodes/bucket), contiguous per-node lists.
// Aggregate: R4-proven sub-wave shfl gather, uint2 (8B) fp8 rows; R13 adds
// ISOLATED VALU micro-opts: packed float2 accumulation (v_pk_fma path) +
// 32-bit byte-offset gather addressing. Fetch pattern identical to proven.
// Structure (R10-proven, 379.4us): fusedA = hist||wprep, scatter, fusedB =
// csr_build||gemm1, agg128, gemm2, agg64, poolcount, head.
// ---------------------------------------------------------------------------

typedef __attribute__((ext_vector_type(8))) short bfrag;     // 8 bf16 = 4 VGPR
typedef __attribute__((ext_vector_type(16))) float f32x16;   // MFMA C/D
typedef __attribute__((ext_vector_type(2))) float floatx2;

__device__ __forceinline__ unsigned short f2bf(float f) {
    unsigned int u = __builtin_bit_cast(unsigned int, f);
    u = (u + 0x7FFFu + ((u >> 16) & 1u)) >> 16;
    return (unsigned short)u;
}
__device__ __forceinline__ float bf2f(unsigned int lo16) {
    unsigned int v = lo16 << 16;
    return __builtin_bit_cast(float, v);
}
__device__ __forceinline__ unsigned char f2fp8(float f) {
    return (unsigned char)(__builtin_amdgcn_cvt_pk_fp8_f32(f, f, 0, false) & 0xFF);
}
// 8 fp8 (uint2) -> 4 f32-pairs, acc2[i] += cvt * (c,c)  (packed fma path).
// Same cvt order / per-feature accumulation sequence as scalar macc8f8.
__device__ __forceinline__ void macc8p(floatx2* a, const uint2 v, float c) {
    floatx2 cc = {c, c};
    a[0] += __builtin_amdgcn_cvt_pk_f32_fp8((int)v.x, false) * cc;
    a[1] += __builtin_amdgcn_cvt_pk_f32_fp8((int)v.x, true) * cc;
    a[2] += __builtin_amdgcn_cvt_pk_f32_fp8((int)v.y, false) * cc;
    a[3] += __builtin_amdgcn_cvt_pk_f32_fp8((int)v.y, true) * cc;
}

// --- pack W[K][NC] fp32 -> bf16 MFMA B-frag order (device body) ---
template <int K, int NC>
__device__ __forceinline__ void wprep_body(int bid, const float* __restrict__ W,
                                           unsigned short* __restrict__ Wf) {
    constexpr int CT = NC / 32, KT = K / 16;
    int idx = bid * 256 + threadIdx.x;
    if (idx >= KT * CT * 64) return;
    int l = idx & 63;
    int fi = idx >> 6;
    int ct = fi % CT, kt = fi / CT;
    int n = ct * 32 + (l & 31);
    int k0 = kt * 16 + 8 * (l >> 5);
    unsigned short v[8];
#pragma unroll
    for (int j = 0; j < 8; ++j) v[j] = f2bf(W[(size_t)(k0 + j) * NC + n]);
    uint4 o;
    o.x = (unsigned)v[0] | ((unsigned)v[1] << 16);
    o.y = (unsigned)v[2] | ((unsigned)v[3] << 16);
    o.z = (unsigned)v[4] | ((unsigned)v[5] << 16);
    o.w = (unsigned)v[6] | ((unsigned)v[7] << 16);
    *(uint4*)&Wf[(size_t)idx * 8] = o;
}

// --- fused A: bucket histogram (blocks < EB) || wprep1 || wprep2 ---
__global__ __launch_bounds__(256) void fusedA_kernel(const int* __restrict__ dst,
                                                     int* __restrict__ bcount, int E, int EB,
                                                     const float* __restrict__ W1,
                                                     unsigned short* __restrict__ Wp1,
                                                     const float* __restrict__ W2,
                                                     unsigned short* __restrict__ Wp2) {
    __shared__ int h[256];
    int b = blockIdx.x;
    int t = threadIdx.x;
    if (b < EB) {
        h[t] = 0;
        __syncthreads();
        int base = b * 4096;
#pragma unroll
        for (int i = 0; i < 16; ++i) {
            int e = base + t + i * 256;
            if (e < E) atomicAdd(&h[dst[e] >> 9], 1);
        }
        __syncthreads();
        if (h[t] > 0) atomicAdd(&bcount[t], h[t]);
    } else if (b < EB + 8) {
        wprep_body<128, 128>(b - EB, W1, Wp1);
    } else {
        wprep_body<128, 64>(b - EB - 8, W2, Wp2);
    }
}

// --- A2: stage packed (src | local_dst<<17) into bucket windows.
//     bstart via redundant block-local scan of bcount; dst reg-cached. ---
__global__ __launch_bounds__(256) void bucket_scatter_kernel(const int* __restrict__ src,
                                                             const int* __restrict__ dst,
                                                             const int* __restrict__ bcount,
                                                             int* __restrict__ bfill,
                                                             unsigned int* __restrict__ stage,
                                                             int E) {
    __shared__ int sc[256];
    __shared__ int hist[256];
    __shared__ int abase[256];
    int t = threadIdx.x;
    int bc = bcount[t];
    sc[t] = bc;
    __syncthreads();
    for (int off = 1; off < 256; off <<= 1) {
        int tmp = 0;
        if (t >= off) tmp = sc[t - off];
        __syncthreads();
        sc[t] += tmp;
        __syncthreads();
    }
    int bstart_t = sc[t] - bc;   // exclusive prefix
    hist[t] = 0;
    __syncthreads();
    int base = blockIdx.x * 4096;
    int dcache[16];
#pragma unroll
    for (int i = 0; i < 16; ++i) {
        int e = base + t + i * 256;
        dcache[i] = (e < E) ? dst[e] : -1;
        if (dcache[i] >= 0) atomicAdd(&hist[dcache[i] >> 9], 1);
    }
    __syncthreads();
    if (hist[t] > 0) {
        int r = atomicAdd(&bfill[t], hist[t]);
        abase[t] = bstart_t + r;
    }
    __syncthreads();
    hist[t] = 0;
    __syncthreads();
#pragma unroll
    for (int i = 0; i < 16; ++i) {
        int e = base + t + i * 256;
        int d = dcache[i];
        if (d >= 0) {
            int b = d >> 9;
            int slot = atomicAdd(&hist[b], 1);
            stage[abase[b] + slot] = (unsigned)src[e] | ((unsigned)(d & 511) << 17);
        }
    }
}

// --- B: per-bucket CSR finalize (device body; 2nd pass hybrid LDS-staged) ---
#define SCAP 14336   // 56 KB LDS edge cache per bucket
__device__ __forceinline__ void csr_build_body(int b, const unsigned int* __restrict__ stage,
                                               const int* __restrict__ bcount,
                                               int* __restrict__ rowstart,
                                               float* __restrict__ dis,
                                               int* __restrict__ csr_src,
                                               int N, int NB, int E) {
    __shared__ int sc[256];
    __shared__ int cnt[512];
    __shared__ int ofs[512];
    __shared__ int psum[256];
    __shared__ unsigned int sedge[SCAP];
    int t = threadIdx.x;
    int bc = bcount[t];
    sc[t] = bc;
    __syncthreads();
    for (int off = 1; off < 256; off <<= 1) {
        int tmp = 0;
        if (t >= off) tmp = sc[t - off];
        __syncthreads();
        sc[t] += tmp;
        __syncthreads();
    }
    int ee = sc[b];              // inclusive prefix at b
    int eb = ee - bcount[b];
    if (b == NB - 1 && t == 0) rowstart[N] = E;
    int node0 = b << 9;
    int nb = min(512, N - node0);
    cnt[t] = 0;
    cnt[t + 256] = 0;
    __syncthreads();
    for (int e = eb + t; e < ee; e += 256) {
        unsigned w = stage[e];
        int le = e - eb;
        if (le < SCAP) sedge[le] = w;
        atomicAdd(&cnt[w >> 17], 1);
    }
    __syncthreads();
    int a = cnt[2 * t], c = cnt[2 * t + 1];
    int ps = a + c;
    psum[t] = ps;
    __syncthreads();
    for (int off = 1; off < 256; off <<= 1) {
        int tmp = 0;
        if (t >= off) tmp = psum[t - off];
        __syncthreads();
        psum[t] += tmp;
        __syncthreads();
    }
    int ex = psum[t] - ps;
    ofs[2 * t] = ex;
    ofs[2 * t + 1] = ex + a;
    if (2 * t < nb) {
        rowstart[node0 + 2 * t] = eb + ex;
        dis[node0 + 2 * t] = rsqrtf(1.f + (float)a);
    }
    if (2 * t + 1 < nb) {
        rowstart[node0 + 2 * t + 1] = eb + ex + a;
        dis[node0 + 2 * t + 1] = rsqrtf(1.f + (float)c);
    }
    __syncthreads();
    for (int e = eb + t; e < ee; e += 256) {
        int le = e - eb;
        unsigned w = (le < SCAP) ? sedge[le] : stage[e];
        int l = w >> 17;
        int slot = atomicAdd(&ofs[l], 1);
        csr_src[eb + slot] = (int)(w & 0x1FFFFu);
    }
}

// --- MFMA GEMM device body: C[M][NC] = A[M][K] @ Wf(frag-packed bf16) ---
template <int K, int NC, bool IN_F32>
__device__ __forceinline__ void gemm_body(int gb, const void* __restrict__ Av,
                                          const unsigned short* __restrict__ Wf,
                                          unsigned char* __restrict__ C, int M) {
    constexpr int KT = K / 16, CT = NC / 32;
    int wid = gb * 4 + (int)(threadIdx.x >> 6);
    int lane = threadIdx.x & 63;
    int row0 = wid * 32;
    if (row0 >= M) return;

    bfrag B[KT][CT];
#pragma unroll
    for (int kt = 0; kt < KT; ++kt)
#pragma unroll
        for (int ct = 0; ct < CT; ++ct)
            B[kt][ct] = *(const bfrag*)&Wf[(size_t)((kt * CT + ct) * 64 + lane) * 8];

    f32x16 acc[CT];
#pragma unroll
    for (int ct = 0; ct < CT; ++ct)
#pragma unroll
        for (int i = 0; i < 16; ++i) acc[ct][i] = 0.f;

    int r = row0 + (lane & 31);
    if (r >= M) r = M - 1;
#pragma unroll
    for (int kt = 0; kt < KT; ++kt) {
        bfrag a;
        if (IN_F32) {
            const float* Arow = &((const float*)Av)[(size_t)r * K + 8 * (lane >> 5)];
            float4 v0 = *(const float4*)&Arow[kt * 16];
            float4 v1 = *(const float4*)&Arow[kt * 16 + 4];
            a[0] = (short)f2bf(v0.x); a[1] = (short)f2bf(v0.y);
            a[2] = (short)f2bf(v0.z); a[3] = (short)f2bf(v0.w);
            a[4] = (short)f2bf(v1.x); a[5] = (short)f2bf(v1.y);
            a[6] = (short)f2bf(v1.z); a[7] = (short)f2bf(v1.w);
        } else {
            const unsigned short* Arow =
                &((const unsigned short*)Av)[(size_t)r * K + 8 * (lane >> 5)];
            a = *(const bfrag*)&Arow[kt * 16];
        }
#pragma unroll
        for (int ct = 0; ct < CT; ++ct)
            acc[ct] = __builtin_amdgcn_mfma_f32_32x32x16_bf16(a, B[kt][ct], acc[ct], 0, 0, 0);
    }

    // C/D layout: col = lane&31, row = (reg&3) + 8*(reg>>2) + 4*(lane>>5)
    int colb = lane & 31;
    int rowq = 4 * (lane >> 5);
#pragma unroll
    for (int ct = 0; ct < CT; ++ct) {
        int col = ct * 32 + colb;
#pragma unroll
        for (int rg = 0; rg < 16; ++rg) {
            int row = row0 + (rg & 3) + 8 * (rg >> 2) + rowq;
            if (row < M) C[(size_t)row * NC + col] = f2fp8(acc[ct][rg]);
        }
    }
}

// --- fused B: csr_build (blocks < NB) || gemm1 (x @ W1 -> fp8) ---
__global__ __launch_bounds__(256) void fusedB_kernel(const unsigned int* __restrict__ stage,
                                                     const int* __restrict__ bcount,
                                                     int* __restrict__ rowstart,
                                                     float* __restrict__ dis,
                                                     int* __restrict__ csr_src,
                                                     int N, int NB, int E,
                                                     const float* __restrict__ x,
                                                     const unsigned short* __restrict__ Wp1,
                                                     unsigned char* __restrict__ hf8) {
    int b = blockIdx.x;
    if (b < NB) {
        csr_build_body(b, stage, bcount, rowstart, dis, csr_src, N, NB, E);
    } else {
        gemm_body<128, 128, true>(b - NB, x, Wp1, hf8, N);
    }
}

// --- standalone GEMM (layer 2) ---
template <int K, int NC, bool IN_F32>
__global__ __launch_bounds__(256) void gemm_mfma_kernel(const void* __restrict__ Av,
                                                        const unsigned short* __restrict__ Wf,
                                                        unsigned char* __restrict__ C,
                                                        int M) {
    gemm_body<K, NC, IN_F32>(blockIdx.x, Av, Wf, C, M);
}

// --- wave-per-node gather aggregation: proven R4 shfl structure + packed
//     float2 accumulation + 32-bit byte-offset addressing.
//     out = relu(d*(sum dis_s*h_s + d*h_n) + bias)   (bf16)
template <int NC>
__global__ __launch_bounds__(256) void aggregate_kernel(const unsigned char* __restrict__ h,
                                                        const float* __restrict__ dis,
                                                        const int* __restrict__ rowstart,
                                                        const int* __restrict__ csr_src,
                                                        const float* __restrict__ bias,
                                                        unsigned short* __restrict__ out,
                                                        int N) {
    constexpr int LPR = NC / 8;             // lanes per row (8B = 8 fp8 each)
    constexpr int RPS = 64 / LPR;           // rows (edges) per step
    constexpr int SH = (NC == 128) ? 7 : 6; // log2(row bytes)
    int wid = (blockIdx.x * blockDim.x + threadIdx.x) >> 6;
    int lane = threadIdx.x & 63;
    if (wid >= N) return;
    int n = wid;
    int sub = lane / LPR;
    int fid = lane % LPR;
    unsigned fb = (unsigned)(fid << 3);     // feature byte offset within row
    float d = dis[n];
    floatx2 acc2[4];
#pragma unroll
    for (int i = 0; i < 4; ++i) acc2[i] = (floatx2){0.f, 0.f};
    if (sub == 0) {
        uint2 hv = *(const uint2*)(h + (((unsigned)n << SH) | fb));
        macc8p(acc2, hv, d);
    }

    int beg = rowstart[n], end = rowstart[n + 1];
    for (int e0 = beg; e0 < end; e0 += 64) {
        int idx = e0 + lane;
        int sv = 0;
        float dv = 0.f;
        if (idx < end) {
            sv = __builtin_nontemporal_load(&csr_src[idx]);
            dv = dis[sv];
        }
        int cnt = min(64, end - e0);
        int j = 0;
        for (; j + 4 * RPS <= cnt; j += 4 * RPS) {
            int ja = j + sub, jb = j + RPS + sub, jc2 = j + 2 * RPS + sub,
                jd = j + 3 * RPS + sub;
            int sa = __shfl(sv, ja); float ca = __shfl(dv, ja);
            int sb = __shfl(sv, jb); float cb = __shfl(dv, jb);
            int sc = __shfl(sv, jc2); float cc = __shfl(dv, jc2);
            int sd = __shfl(sv, jd); float cd = __shfl(dv, jd);
            uint2 va = *(const uint2*)(h + (((unsigned)sa << SH) | fb));
            uint2 vb = *(const uint2*)(h + (((unsigned)sb << SH) | fb));
            uint2 vc = *(const uint2*)(h + (((unsigned)sc << SH) | fb));
            uint2 vd = *(const uint2*)(h + (((unsigned)sd << SH) | fb));
            macc8p(acc2, va, ca);
            macc8p(acc2, vb, cb);
            macc8p(acc2, vc, cc);
            macc8p(acc2, vd, cd);
        }
        for (; j + 2 * RPS <= cnt; j += 2 * RPS) {
            int ja = j + sub, jb = j + RPS + sub;
            int sa = __shfl(sv, ja); float ca = __shfl(dv, ja);
            int sb = __shfl(sv, jb); float cb = __shfl(dv, jb);
            uint2 va = *(const uint2*)(h + (((unsigned)sa << SH) | fb));
            uint2 vb = *(const uint2*)(h + (((unsigned)sb << SH) | fb));
            macc8p(acc2, va, ca);
            macc8p(acc2, vb, cb);
        }
        for (; j < cnt; j += RPS) {
            int jj = j + sub;
            int jc = min(jj, cnt - 1);
            int s = __shfl(sv, jc);
            float c = __shfl(dv, jc);
            if (jj >= cnt) c = 0.f;
            uint2 v = *(const uint2*)(h + (((unsigned)s << SH) | fb));
            macc8p(acc2, v, c);
        }
    }
#pragma unroll
    for (int m = LPR; m < 64; m <<= 1) {
#pragma unroll
        for (int i = 0; i < 4; ++i) {
            acc2[i].x += __shfl_xor(acc2[i].x, m);
            acc2[i].y += __shfl_xor(acc2[i].y, m);
        }
    }
    if (sub == 0) {
        const float4 bv0 = *(const float4*)&bias[fid * 8 + 0];
        const float4 bv1 = *(const float4*)&bias[fid * 8 + 4];
        float r[8];
        r[0] = fmaxf(acc2[0].x * d + bv0.x, 0.f);
        r[1] = fmaxf(acc2[0].y * d + bv0.y, 0.f);
        r[2] = fmaxf(acc2[1].x * d + bv0.z, 0.f);
        r[3] = fmaxf(acc2[1].y * d + bv0.w, 0.f);
        r[4] = fmaxf(acc2[2].x * d + bv1.x, 0.f);
        r[5] = fmaxf(acc2[2].y * d + bv1.y, 0.f);
        r[6] = fmaxf(acc2[3].x * d + bv1.z, 0.f);
        r[7] = fmaxf(acc2[3].y * d + bv1.w, 0.f);
        uint4 o;
        o.x = (unsigned)f2bf(r[0]) | ((unsigned)f2bf(r[1]) << 16);
        o.y = (unsigned)f2bf(r[2]) | ((unsigned)f2bf(r[3]) << 16);
        o.z = (unsigned)f2bf(r[4]) | ((unsigned)f2bf(r[5]) << 16);
        o.w = (unsigned)f2bf(r[6]) | ((unsigned)f2bf(r[7]) << 16);
        *(uint4*)&out[(size_t)n * NC + fid * 8] = o;
    }
}

// --- fused pool+count: blocks < PB pool h2 (256thr, 4-way node stride);
//     blocks >= PB histogram batch into gcnt. (batch sorted) ---
__global__ __launch_bounds__(256) void poolcount_kernel(const unsigned short* __restrict__ h2,
                                                        const int* __restrict__ batch,
                                                        float* __restrict__ gsum,
                                                        int* __restrict__ gcnt,
                                                        int N, int PB) {
    int t = threadIdx.x;
    if ((int)blockIdx.x < PB) {
        int fid = t & 63;
        int strip = t >> 6;
        int n0 = blockIdx.x * 128;
        int nend = min(n0 + 128, N);
        int n = n0 + strip;
        if (n < nend) {
            float acc = 0.f;
            int gcur = batch[n];
            for (; n < nend; n += 4) {
                int g = batch[n];
                if (g != gcur) {
                    atomicAdd(&gsum[gcur * 64 + fid], acc);
                    acc = 0.f;
                    gcur = g;
                }
                acc += bf2f(h2[(size_t)n * 64 + fid]);
            }
            atomicAdd(&gsum[gcur * 64 + fid], acc);
        }
    } else {
        __shared__ int lc[64];
        if (t < 64) lc[t] = 0;
        __syncthreads();
        int n = ((int)blockIdx.x - PB) * 256 + t;
        if (n < N) atomicAdd(&lc[batch[n]], 1);
        __syncthreads();
        if (t < 64 && lc[t] > 0) atomicAdd(&gcnt[t], lc[t]);
    }
}

// --- head: ge = pooled_h2 @ Wf1 + bf1 ; ic = ge @ Wf2 + bf2 ---
__global__ __launch_bounds__(128) void head_kernel(const float* __restrict__ gsum,
                                                   const int* __restrict__ gcnt,
                                                   const float* __restrict__ Wf1,
                                                   const float* __restrict__ bf1,
                                                   const float* __restrict__ Wf2,
                                                   const float* __restrict__ bf2,
                                                   float* __restrict__ out) {
    __shared__ float ph[64];
    __shared__ float red0[128], red1[128];
    int g = blockIdx.x, f = threadIdx.x;
    if (f < 64) ph[f] = gsum[g * 64 + f] / (float)max(gcnt[g], 1);
    __syncthreads();
    float ge = bf1[f];
#pragma unroll 8
    for (int k = 0; k < 64; ++k) ge += ph[k] * Wf1[k * 128 + f];
    out[g * 128 + f] = ge;
    red0[f] = ge * Wf2[f * 2 + 0];
    red1[f] = ge * Wf2[f * 2 + 1];
    __syncthreads();
    for (int off = 64; off > 0; off >>= 1) {
        if (f < off) { red0[f] += red0[f + off]; red1[f] += red1[f + off]; }
        __syncthreads();
    }
    if (f == 0) {
        out[8192 + 1 + g * 2 + 0] = red0[0] + bf2[0];
        out[8192 + 1 + g * 2 + 1] = red1[0] + bf2[1];
        if (g == 0) out[8192] = 0.f;
    }
}

extern "C" void kernel_launch(void* const* d_in, const int* in_sizes, int n_in,
                              void* d_out, int out_size, void* d_ws, size_t ws_size,
                              hipStream_t stream) {
    const float* x   = (const float*)d_in[0];
    const float* W1  = (const float*)d_in[1];
    const float* b1  = (const float*)d_in[2];
    const float* W2  = (const float*)d_in[3];
    const float* b2  = (const float*)d_in[4];
    const float* Wf1 = (const float*)d_in[5];
    const float* bf1 = (const float*)d_in[6];
    const float* Wf2 = (const float*)d_in[7];
    const float* bf2 = (const float*)d_in[8];
    const int* edge  = (const int*)d_in[9];
    const int* batch = (const int*)d_in[10];

    const int N = in_sizes[10];      // 100000
    const int E = in_sizes[9] / 2;   // 3200000
    const int* srcA = edge;
    const int* dstA = edge + E;
    float* out = (float*)d_out;

    const int NB = (N + 511) >> 9;   // dst buckets of 512 nodes

    char* p = (char*)d_ws;
    auto alloc = [&](size_t bytes) {
        char* r = p;
        p += (bytes + 255) & ~(size_t)255;
        return r;
    };
    float* gsum     = (float*)alloc(64 * 64 * 4);
    int*   gcnt     = (int*)alloc(64 * 4);
    int*   bcount   = (int*)alloc(256 * 4);
    int*   bfill    = (int*)alloc(256 * 4);
    size_t zbytes   = (size_t)(p - (char*)d_ws);
    float* dis      = (float*)alloc((size_t)N * 4);
    int*   rowstart = (int*)alloc((size_t)(N + 1) * 4);
    unsigned short* Wp1 = (unsigned short*)alloc(8 * 4 * 64 * 8 * 2);  // 32 KB
    unsigned short* Wp2 = (unsigned short*)alloc(8 * 2 * 64 * 8 * 2);  // 16 KB
    unsigned int* stage = (unsigned int*)alloc((size_t)E * 4);
    int*   csr_src  = (int*)alloc((size_t)E * 4);
    unsigned char*  hf8   = (unsigned char*)alloc((size_t)N * 128);      // h then g (fp8)
    unsigned short* h1b   = (unsigned short*)alloc((size_t)N * 128 * 2); // h1 (bf16)
    unsigned short* h2b   = (unsigned short*)alloc((size_t)N * 64 * 2);  // h2 (bf16)

    (void)hipMemsetAsync(d_ws, 0, zbytes, stream);

    const int EB = (E + 4095) / 4096;
    const int GB = (N + 127) / 128;   // 4 waves x 32 rows per block
    // hist || weight-prep (independent, both low-VGPR)
    fusedA_kernel<<<EB + 12, 256, 0, stream>>>(dstA, bcount, E, EB, W1, Wp1, W2, Wp2);
    bucket_scatter_kernel<<<EB, 256, 0, stream>>>(srcA, dstA, bcount, bfill, stage, E);
    // csr_build || gemm1 (independent; build grid 196 < 256 CUs)
    fusedB_kernel<<<NB + GB, 256, 0, stream>>>(stage, bcount, rowstart, dis, csr_src,
                                               N, NB, E, x, Wp1, hf8);
    // layer 1 aggregate: h1 = relu(d*(sum+self) + b1) (bf16)
    aggregate_kernel<128><<<(N + 3) / 4, 256, 0, stream>>>(hf8, dis, rowstart, csr_src,
                                                           b1, h1b, N);
    // layer 2: g = h1@W2 (bf16 in, fp8 out) ; h2 = relu(...) (bf16)
    gemm_mfma_kernel<128, 64, false><<<GB, 256, 0, stream>>>(h1b, Wp2, hf8, N);
    aggregate_kernel<64><<<(N + 3) / 4, 256, 0, stream>>>(hf8, dis, rowstart, csr_src,
                                                          b2, h2b, N);
    // head: pool(h2)||count, then tiny GEMMs
    const int PB = (N + 127) / 128;
    const int CB = (N + 255) / 256;
    poolcount_kernel<<<PB + CB, 256, 0, stream>>>(h2b, batch, gsum, gcnt, N, PB);
    head_kernel<<<64, 128, 0, stream>>>(gsum, gcnt, Wf1, bf1, Wf2, bf2, out);
}